// Round 1
// baseline (552.143 us; speedup 1.0000x reference)
//
#include <hip/hip_runtime.h>
#include <math.h>

// ---------------------------------------------------------------------------
// GATv2 2-layer GNN, fp32. N=50000, E=800000, F=128 (all dims).
// Pipeline per call:
//   1. build CSR by dst (count -> scan -> scatter)      [shared by both layers]
//   2. GEMM x @ {Wl1,Wr1} + bias -> bufA (xl), bufB (xr)
//   3. aggregate: online-softmax over in-edges -> bufC = relu(out + b1)
//   4. GEMM bufC @ {Wl2,Wr2} + bias -> bufA, bufB
//   5. aggregate -> d_out (+ b2, no relu)
// ---------------------------------------------------------------------------

__global__ void zero_int_kernel(int* __restrict__ p, int n) {
    int i = blockIdx.x * blockDim.x + threadIdx.x;
    if (i < n) p[i] = 0;
}

__global__ void count_deg_kernel(const int* __restrict__ dst, int* __restrict__ deg, int E) {
    int i = blockIdx.x * blockDim.x + threadIdx.x;
    if (i < E) atomicAdd(&deg[dst[i]], 1);
}

// Single-block exclusive scan over n entries (chunks of 1024, wave-shuffle scan).
__global__ __launch_bounds__(1024) void scan_deg_kernel(const int* __restrict__ deg,
                                                        int* __restrict__ row_ptr,
                                                        int* __restrict__ writeidx, int n) {
    __shared__ int wsumExcl[16];
    __shared__ int sTotal;
    int tid = threadIdx.x;
    int lane = tid & 63;
    int wid = tid >> 6;
    int carry = 0;
    for (int base = 0; base < n; base += 1024) {
        int idx = base + tid;
        int v = (idx < n) ? deg[idx] : 0;
        int incl = v;
        #pragma unroll
        for (int off = 1; off < 64; off <<= 1) {
            int t = __shfl_up(incl, off);
            if (lane >= off) incl += t;
        }
        if (lane == 63) wsumExcl[wid] = incl;  // wave totals (inclusive)
        __syncthreads();
        if (tid < 16) {
            int w = wsumExcl[tid];
            int iw = w;
            #pragma unroll
            for (int off = 1; off < 16; off <<= 1) {
                int t = __shfl_up(iw, off);
                if (tid >= off) iw += t;
            }
            wsumExcl[tid] = iw - w;  // exclusive wave offset
            if (tid == 15) sTotal = iw;
        }
        __syncthreads();
        int excl = carry + wsumExcl[wid] + (incl - v);
        if (idx < n) { row_ptr[idx] = excl; writeidx[idx] = excl; }
        carry += sTotal;
        __syncthreads();  // protect LDS for next chunk
    }
    if (tid == 0) row_ptr[n] = carry;
}

__global__ void scatter_edges_kernel(const int* __restrict__ src, const int* __restrict__ dst,
                                     int* __restrict__ writeidx, int* __restrict__ csr_src, int E) {
    int i = blockIdx.x * blockDim.x + threadIdx.x;
    if (i < E) {
        int d = dst[i];
        int pos = atomicAdd(&writeidx[d], 1);
        csr_src[pos] = src[i];
    }
}

// ---------------------------------------------------------------------------
// fp32 GEMM: out = X @ W + b, X is [Nrows x 128], W is [128 x 128] row-major.
// blockIdx.y in {0,1} selects (W0,b0,out0) / (W1,b1,out1) so the X tile staging
// is shared between the Wl and Wr transforms of a layer.
// 128x128 block tile, 8x8 micro-tile, BK=32, 256 threads.
// ---------------------------------------------------------------------------
__global__ __launch_bounds__(256) void gemm_dual_kernel(
    const float* __restrict__ X,
    const float* __restrict__ W0, const float* __restrict__ b0, float* __restrict__ out0,
    const float* __restrict__ W1, const float* __restrict__ b1, float* __restrict__ out1,
    int Nrows) {
    const float* W = blockIdx.y ? W1 : W0;
    const float* bias = blockIdx.y ? b1 : b0;
    float* out = blockIdx.y ? out1 : out0;

    __shared__ float xs[32][128];   // transposed: xs[k][m]
    __shared__ float wsh[32][128];  // wsh[k][n]

    int tid = threadIdx.x;
    int tx = tid & 15;   // col group: cols tx*8 .. tx*8+7
    int ty = tid >> 4;   // row group: rows ty*8 .. ty*8+7
    int m0 = blockIdx.x * 128;

    float acc[8][8] = {{0.f}};

    for (int k0 = 0; k0 < 128; k0 += 32) {
        // stage X tile (transposed into xs[k][m])
        #pragma unroll
        for (int r = 0; r < 4; ++r) {
            int row = (tid >> 3) + r * 32;
            int kseg = (tid & 7) * 4;
            int gr = m0 + row;
            if (gr >= Nrows) gr = Nrows - 1;  // clamp; stores are guarded
            const float4 v = *(const float4*)&X[(size_t)gr * 128 + k0 + kseg];
            xs[kseg + 0][row] = v.x;
            xs[kseg + 1][row] = v.y;
            xs[kseg + 2][row] = v.z;
            xs[kseg + 3][row] = v.w;
        }
        // stage W tile
        #pragma unroll
        for (int r = 0; r < 4; ++r) {
            int wrow = (tid >> 5) + r * 8;
            int wcol = (tid & 31) * 4;
            *(float4*)&wsh[wrow][wcol] = *(const float4*)&W[(size_t)(k0 + wrow) * 128 + wcol];
        }
        __syncthreads();
        #pragma unroll
        for (int k = 0; k < 32; ++k) {
            float a[8], b[8];
            *(float4*)&a[0] = *(float4*)&xs[k][ty * 8];
            *(float4*)&a[4] = *(float4*)&xs[k][ty * 8 + 4];
            *(float4*)&b[0] = *(float4*)&wsh[k][tx * 8];
            *(float4*)&b[4] = *(float4*)&wsh[k][tx * 8 + 4];
            #pragma unroll
            for (int i = 0; i < 8; ++i)
                #pragma unroll
                for (int j = 0; j < 8; ++j)
                    acc[i][j] += a[i] * b[j];
        }
        __syncthreads();
    }

    float bv[8];
    *(float4*)&bv[0] = *(const float4*)&bias[tx * 8];
    *(float4*)&bv[4] = *(const float4*)&bias[tx * 8 + 4];
    #pragma unroll
    for (int i = 0; i < 8; ++i) {
        int gr = m0 + ty * 8 + i;
        if (gr < Nrows) {
            float4 o0 = {acc[i][0] + bv[0], acc[i][1] + bv[1], acc[i][2] + bv[2], acc[i][3] + bv[3]};
            float4 o1 = {acc[i][4] + bv[4], acc[i][5] + bv[5], acc[i][6] + bv[6], acc[i][7] + bv[7]};
            *(float4*)&out[(size_t)gr * 128 + tx * 8] = o0;
            *(float4*)&out[(size_t)gr * 128 + tx * 8 + 4] = o1;
        }
    }
}

// ---------------------------------------------------------------------------
// Per-node aggregation with online softmax. One wave (64 lanes) per node,
// lane covers 2 feature dims (float2). No atomics; deterministic.
// out[n] = (sum_e exp(s_e - m) * xl[src_e]) / denom + bias   [, relu]
// s_e = att . leaky_relu(xl[src_e] + xr[n], 0.2)
// ---------------------------------------------------------------------------
__global__ __launch_bounds__(256) void gat_aggregate_kernel(
    const float* __restrict__ xl, const float* __restrict__ xr,
    const float* __restrict__ att, const float* __restrict__ bias,
    const int* __restrict__ row_ptr, const int* __restrict__ csr_src,
    float* __restrict__ out, int N, int applyRelu) {
    int wid = threadIdx.x >> 6;
    int lane = threadIdx.x & 63;
    int node = blockIdx.x * 4 + wid;
    if (node >= N) return;

    const float2* xl2 = (const float2*)xl;
    float2 xrv = ((const float2*)xr)[(size_t)node * 64 + lane];
    float2 attv = ((const float2*)att)[lane];

    int beg = row_ptr[node];
    int end = row_ptr[node + 1];

    float m = -INFINITY;
    float dsum = 0.f;
    float accx = 0.f, accy = 0.f;

    for (int e = beg; e < end; ++e) {
        int s = csr_src[e];
        float2 v = xl2[(size_t)s * 64 + lane];
        float ex = v.x + xrv.x;
        float ey = v.y + xrv.y;
        ex = ex > 0.f ? ex : 0.2f * ex;
        ey = ey > 0.f ? ey : 0.2f * ey;
        float part = ex * attv.x + ey * attv.y;
        #pragma unroll
        for (int off = 32; off > 0; off >>= 1) part += __shfl_xor(part, off);
        float mnew = fmaxf(m, part);
        float scale = __expf(m - mnew);   // first iter: exp(-inf)=0
        float p = __expf(part - mnew);
        dsum = dsum * scale + p;
        accx = accx * scale + p * v.x;
        accy = accy * scale + p * v.y;
        m = mnew;
    }

    float inv = dsum > 0.f ? 1.f / dsum : 0.f;
    float2 bv = ((const float2*)bias)[lane];
    float ox = accx * inv + bv.x;
    float oy = accy * inv + bv.y;
    if (applyRelu) { ox = fmaxf(ox, 0.f); oy = fmaxf(oy, 0.f); }
    ((float2*)out)[(size_t)node * 64 + lane] = make_float2(ox, oy);
}

// ---------------------------------------------------------------------------

extern "C" void kernel_launch(void* const* d_in, const int* in_sizes, int n_in,
                              void* d_out, int out_size, void* d_ws, size_t ws_size,
                              hipStream_t stream) {
    const float* x    = (const float*)d_in[0];
    const int* eidx   = (const int*)d_in[1];
    const float* Wl1  = (const float*)d_in[2];
    const float* bl1  = (const float*)d_in[3];
    const float* Wr1  = (const float*)d_in[4];
    const float* br1  = (const float*)d_in[5];
    const float* att1 = (const float*)d_in[6];
    const float* b1   = (const float*)d_in[7];
    const float* Wl2  = (const float*)d_in[8];
    const float* bl2  = (const float*)d_in[9];
    const float* Wr2  = (const float*)d_in[10];
    const float* br2  = (const float*)d_in[11];
    const float* att2 = (const float*)d_in[12];
    const float* b2   = (const float*)d_in[13];

    const int N = in_sizes[0] / 128;
    const int E = in_sizes[1] / 2;
    const int* src = eidx;
    const int* dst = eidx + E;

    // workspace layout
    size_t NF = (size_t)N * 128;
    float* bufA = (float*)d_ws;        // xl
    float* bufB = bufA + NF;           // xr
    float* bufC = bufB + NF;           // h
    int* deg      = (int*)(bufC + NF); // [N]
    int* row_ptr  = deg + N;           // [N+1]
    int* writeidx = row_ptr + (N + 1); // [N]
    int* csr_src  = writeidx + N;      // [E]

    float* outF = (float*)d_out;

    // --- CSR build (shared by both layers) ---
    zero_int_kernel<<<(N + 255) / 256, 256, 0, stream>>>(deg, N);
    count_deg_kernel<<<(E + 255) / 256, 256, 0, stream>>>(dst, deg, E);
    scan_deg_kernel<<<1, 1024, 0, stream>>>(deg, row_ptr, writeidx, N);
    scatter_edges_kernel<<<(E + 255) / 256, 256, 0, stream>>>(src, dst, writeidx, csr_src, E);

    dim3 gemmGrid((N + 127) / 128, 2);
    dim3 aggGrid((N + 3) / 4);

    // --- layer 1 ---
    gemm_dual_kernel<<<gemmGrid, 256, 0, stream>>>(x, Wl1, bl1, bufA, Wr1, br1, bufB, N);
    gat_aggregate_kernel<<<aggGrid, 256, 0, stream>>>(bufA, bufB, att1, b1, row_ptr, csr_src,
                                                      bufC, N, 1);
    // --- layer 2 ---
    gemm_dual_kernel<<<gemmGrid, 256, 0, stream>>>(bufC, Wl2, bl2, bufA, Wr2, br2, bufB, N);
    gat_aggregate_kernel<<<aggGrid, 256, 0, stream>>>(bufA, bufB, att2, b2, row_ptr, csr_src,
                                                      outF, N, 0);
}

// Round 2
// 412.231 us; speedup vs baseline: 1.3394x; 1.3394x over previous
//
#include <hip/hip_runtime.h>
#include <math.h>

// ---------------------------------------------------------------------------
// GATv2 2-layer GNN, fp32. N=50000, E=800000, F=128 (all dims).
// Pipeline per call:
//   1. build CSR by dst (count -> 3-kernel scan -> scatter)
//   2. GEMM x @ {Wl1,Wr1} + bias -> bufA (xl), bufB (xr)
//   3. aggregate: online-softmax over in-edges (4-edge batched) -> bufC
//   4. GEMM bufC @ {Wl2,Wr2} + bias -> bufA, bufB
//   5. aggregate -> d_out (+ b2, no relu)
// ---------------------------------------------------------------------------

__global__ void zero_int_kernel(int* __restrict__ p, int n) {
    int i = blockIdx.x * blockDim.x + threadIdx.x;
    if (i < n) p[i] = 0;
}

__global__ void count_deg_kernel(const int* __restrict__ dst, int* __restrict__ deg, int E) {
    int i = blockIdx.x * blockDim.x + threadIdx.x;
    if (i < E) atomicAdd(&deg[dst[i]], 1);
}

// --- hierarchical scan: pass 1 -- per-block (256 nodes) sums ---
__global__ __launch_bounds__(256) void scan_blocksum_kernel(const int* __restrict__ deg,
                                                            int* __restrict__ blockSums, int n) {
    __shared__ int wsum[4];
    int tid = threadIdx.x;
    int idx = blockIdx.x * 256 + tid;
    int v = (idx < n) ? deg[idx] : 0;
    int lane = tid & 63, wid = tid >> 6;
    #pragma unroll
    for (int off = 32; off > 0; off >>= 1) v += __shfl_xor(v, off);
    if (lane == 0) wsum[wid] = v;
    __syncthreads();
    if (tid == 0) blockSums[blockIdx.x] = wsum[0] + wsum[1] + wsum[2] + wsum[3];
}

// --- pass 2 -- single-block exclusive scan of block sums (chunked, any n) ---
__global__ __launch_bounds__(256) void scan_sums_kernel(int* __restrict__ blockSums,
                                                        int* __restrict__ blockOffs,
                                                        int* __restrict__ totalOut, int n) {
    __shared__ int wsumExcl[4];
    __shared__ int sTotal;
    int tid = threadIdx.x, lane = tid & 63, wid = tid >> 6;
    int carry = 0;
    for (int base = 0; base < n; base += 256) {
        int idx = base + tid;
        int v = (idx < n) ? blockSums[idx] : 0;
        int incl = v;
        #pragma unroll
        for (int off = 1; off < 64; off <<= 1) {
            int t = __shfl_up(incl, off);
            if (lane >= off) incl += t;
        }
        if (lane == 63) wsumExcl[wid] = incl;
        __syncthreads();
        if (tid == 0) {
            int a = wsumExcl[0], b = wsumExcl[1], c = wsumExcl[2], d = wsumExcl[3];
            wsumExcl[0] = 0; wsumExcl[1] = a; wsumExcl[2] = a + b; wsumExcl[3] = a + b + c;
            sTotal = a + b + c + d;
        }
        __syncthreads();
        if (idx < n) blockOffs[idx] = carry + wsumExcl[wid] + (incl - v);
        carry += sTotal;
        __syncthreads();
    }
    if (tid == 0) *totalOut = carry;
}

// --- pass 3 -- local scan + block offset -> row_ptr / writeidx ---
__global__ __launch_bounds__(256) void scan_apply_kernel(const int* __restrict__ deg,
                                                         const int* __restrict__ blockOffs,
                                                         int* __restrict__ row_ptr,
                                                         int* __restrict__ writeidx, int n) {
    __shared__ int wsum[4];
    int tid = threadIdx.x, lane = tid & 63, wid = tid >> 6;
    int idx = blockIdx.x * 256 + tid;
    int v = (idx < n) ? deg[idx] : 0;
    int incl = v;
    #pragma unroll
    for (int off = 1; off < 64; off <<= 1) {
        int t = __shfl_up(incl, off);
        if (lane >= off) incl += t;
    }
    if (lane == 63) wsum[wid] = incl;
    __syncthreads();
    int woff = 0;
    #pragma unroll
    for (int w = 0; w < 4; ++w) woff += (w < wid) ? wsum[w] : 0;
    int excl = blockOffs[blockIdx.x] + woff + (incl - v);
    if (idx < n) { row_ptr[idx] = excl; writeidx[idx] = excl; }
}

__global__ void scatter_edges_kernel(const int* __restrict__ src, const int* __restrict__ dst,
                                     int* __restrict__ writeidx, int* __restrict__ csr_src, int E) {
    int i = blockIdx.x * blockDim.x + threadIdx.x;
    if (i < E) {
        int d = dst[i];
        int pos = atomicAdd(&writeidx[d], 1);
        csr_src[pos] = src[i];
    }
}

// ---------------------------------------------------------------------------
// fp32 GEMM (unchanged this round): out = X @ W + b.
// ---------------------------------------------------------------------------
__global__ __launch_bounds__(256) void gemm_dual_kernel(
    const float* __restrict__ X,
    const float* __restrict__ W0, const float* __restrict__ b0, float* __restrict__ out0,
    const float* __restrict__ W1, const float* __restrict__ b1, float* __restrict__ out1,
    int Nrows) {
    const float* W = blockIdx.y ? W1 : W0;
    const float* bias = blockIdx.y ? b1 : b0;
    float* out = blockIdx.y ? out1 : out0;

    __shared__ float xs[32][128];
    __shared__ float wsh[32][128];

    int tid = threadIdx.x;
    int tx = tid & 15;
    int ty = tid >> 4;
    int m0 = blockIdx.x * 128;

    float acc[8][8] = {{0.f}};

    for (int k0 = 0; k0 < 128; k0 += 32) {
        #pragma unroll
        for (int r = 0; r < 4; ++r) {
            int row = (tid >> 3) + r * 32;
            int kseg = (tid & 7) * 4;
            int gr = m0 + row;
            if (gr >= Nrows) gr = Nrows - 1;
            const float4 v = *(const float4*)&X[(size_t)gr * 128 + k0 + kseg];
            xs[kseg + 0][row] = v.x;
            xs[kseg + 1][row] = v.y;
            xs[kseg + 2][row] = v.z;
            xs[kseg + 3][row] = v.w;
        }
        #pragma unroll
        for (int r = 0; r < 4; ++r) {
            int wrow = (tid >> 5) + r * 8;
            int wcol = (tid & 31) * 4;
            *(float4*)&wsh[wrow][wcol] = *(const float4*)&W[(size_t)(k0 + wrow) * 128 + wcol];
        }
        __syncthreads();
        #pragma unroll
        for (int k = 0; k < 32; ++k) {
            float a[8], b[8];
            *(float4*)&a[0] = *(float4*)&xs[k][ty * 8];
            *(float4*)&a[4] = *(float4*)&xs[k][ty * 8 + 4];
            *(float4*)&b[0] = *(float4*)&wsh[k][tx * 8];
            *(float4*)&b[4] = *(float4*)&wsh[k][tx * 8 + 4];
            #pragma unroll
            for (int i = 0; i < 8; ++i)
                #pragma unroll
                for (int j = 0; j < 8; ++j)
                    acc[i][j] += a[i] * b[j];
        }
        __syncthreads();
    }

    float bv[8];
    *(float4*)&bv[0] = *(const float4*)&bias[tx * 8];
    *(float4*)&bv[4] = *(const float4*)&bias[tx * 8 + 4];
    #pragma unroll
    for (int i = 0; i < 8; ++i) {
        int gr = m0 + ty * 8 + i;
        if (gr < Nrows) {
            float4 o0 = {acc[i][0] + bv[0], acc[i][1] + bv[1], acc[i][2] + bv[2], acc[i][3] + bv[3]};
            float4 o1 = {acc[i][4] + bv[4], acc[i][5] + bv[5], acc[i][6] + bv[6], acc[i][7] + bv[7]};
            *(float4*)&out[(size_t)gr * 128 + tx * 8] = o0;
            *(float4*)&out[(size_t)gr * 128 + tx * 8 + 4] = o1;
        }
    }
}

// ---------------------------------------------------------------------------
// Per-node aggregation, online softmax, 4-edge batched for ILP.
// One wave per node, lane covers 2 feature dims. Indices for up to 64 edges
// are loaded with ONE coalesced lane-load per chunk and broadcast via shfl.
// ---------------------------------------------------------------------------
__global__ __launch_bounds__(256) void gat_aggregate_kernel(
    const float* __restrict__ xl, const float* __restrict__ xr,
    const float* __restrict__ att, const float* __restrict__ bias,
    const int* __restrict__ row_ptr, const int* __restrict__ csr_src,
    float* __restrict__ out, int N, int applyRelu) {
    int wid = threadIdx.x >> 6;
    int lane = threadIdx.x & 63;
    int node = blockIdx.x * 4 + wid;
    if (node >= N) return;

    const float2* xl2 = (const float2*)xl;
    float2 xrv = ((const float2*)xr)[(size_t)node * 64 + lane];
    float2 attv = ((const float2*)att)[lane];

    int beg = row_ptr[node];
    int end = row_ptr[node + 1];

    float m = -INFINITY;
    float dsum = 0.f;
    float accx = 0.f, accy = 0.f;

    for (int cbase = beg; cbase < end; cbase += 64) {
        int cnt = end - cbase;
        if (cnt > 64) cnt = 64;
        int myidx = (lane < cnt) ? csr_src[cbase + lane] : 0;  // coalesced

        int e = 0;
        for (; e + 4 <= cnt; e += 4) {
            int s0 = __shfl(myidx, e + 0);
            int s1 = __shfl(myidx, e + 1);
            int s2 = __shfl(myidx, e + 2);
            int s3 = __shfl(myidx, e + 3);
            float2 v0 = xl2[(size_t)s0 * 64 + lane];
            float2 v1 = xl2[(size_t)s1 * 64 + lane];
            float2 v2 = xl2[(size_t)s2 * 64 + lane];
            float2 v3 = xl2[(size_t)s3 * 64 + lane];

            float ex, ey;
            ex = v0.x + xrv.x; ey = v0.y + xrv.y;
            ex = ex > 0.f ? ex : 0.2f * ex; ey = ey > 0.f ? ey : 0.2f * ey;
            float p0 = ex * attv.x + ey * attv.y;
            ex = v1.x + xrv.x; ey = v1.y + xrv.y;
            ex = ex > 0.f ? ex : 0.2f * ex; ey = ey > 0.f ? ey : 0.2f * ey;
            float p1 = ex * attv.x + ey * attv.y;
            ex = v2.x + xrv.x; ey = v2.y + xrv.y;
            ex = ex > 0.f ? ex : 0.2f * ex; ey = ey > 0.f ? ey : 0.2f * ey;
            float p2 = ex * attv.x + ey * attv.y;
            ex = v3.x + xrv.x; ey = v3.y + xrv.y;
            ex = ex > 0.f ? ex : 0.2f * ex; ey = ey > 0.f ? ey : 0.2f * ey;
            float p3 = ex * attv.x + ey * attv.y;

            // 4 independent butterflies, interleaved for pipelining
            #pragma unroll
            for (int off = 32; off > 0; off >>= 1) {
                p0 += __shfl_xor(p0, off);
                p1 += __shfl_xor(p1, off);
                p2 += __shfl_xor(p2, off);
                p3 += __shfl_xor(p3, off);
            }

            float mnew = fmaxf(fmaxf(fmaxf(p0, p1), fmaxf(p2, p3)), m);
            float scale = __expf(m - mnew);  // first batch: exp(-inf)=0
            float e0 = __expf(p0 - mnew);
            float e1 = __expf(p1 - mnew);
            float e2 = __expf(p2 - mnew);
            float e3 = __expf(p3 - mnew);
            dsum = dsum * scale + (e0 + e1) + (e2 + e3);
            accx = accx * scale + e0 * v0.x + e1 * v1.x + e2 * v2.x + e3 * v3.x;
            accy = accy * scale + e0 * v0.y + e1 * v1.y + e2 * v2.y + e3 * v3.y;
            m = mnew;
        }
        for (; e < cnt; ++e) {
            int s = __shfl(myidx, e);
            float2 v = xl2[(size_t)s * 64 + lane];
            float ex = v.x + xrv.x;
            float ey = v.y + xrv.y;
            ex = ex > 0.f ? ex : 0.2f * ex;
            ey = ey > 0.f ? ey : 0.2f * ey;
            float part = ex * attv.x + ey * attv.y;
            #pragma unroll
            for (int off = 32; off > 0; off >>= 1) part += __shfl_xor(part, off);
            float mnew = fmaxf(m, part);
            float scale = __expf(m - mnew);
            float p = __expf(part - mnew);
            dsum = dsum * scale + p;
            accx = accx * scale + p * v.x;
            accy = accy * scale + p * v.y;
            m = mnew;
        }
    }

    float inv = dsum > 0.f ? 1.f / dsum : 0.f;
    float2 bv = ((const float2*)bias)[lane];
    float ox = accx * inv + bv.x;
    float oy = accy * inv + bv.y;
    if (applyRelu) { ox = fmaxf(ox, 0.f); oy = fmaxf(oy, 0.f); }
    ((float2*)out)[(size_t)node * 64 + lane] = make_float2(ox, oy);
}

// ---------------------------------------------------------------------------

extern "C" void kernel_launch(void* const* d_in, const int* in_sizes, int n_in,
                              void* d_out, int out_size, void* d_ws, size_t ws_size,
                              hipStream_t stream) {
    const float* x    = (const float*)d_in[0];
    const int* eidx   = (const int*)d_in[1];
    const float* Wl1  = (const float*)d_in[2];
    const float* bl1  = (const float*)d_in[3];
    const float* Wr1  = (const float*)d_in[4];
    const float* br1  = (const float*)d_in[5];
    const float* att1 = (const float*)d_in[6];
    const float* b1   = (const float*)d_in[7];
    const float* Wl2  = (const float*)d_in[8];
    const float* bl2  = (const float*)d_in[9];
    const float* Wr2  = (const float*)d_in[10];
    const float* br2  = (const float*)d_in[11];
    const float* att2 = (const float*)d_in[12];
    const float* b2   = (const float*)d_in[13];

    const int N = in_sizes[0] / 128;
    const int E = in_sizes[1] / 2;
    const int* src = eidx;
    const int* dst = eidx + E;

    const int nBlk = (N + 255) / 256;  // scan blocks

    // workspace layout
    size_t NF = (size_t)N * 128;
    float* bufA = (float*)d_ws;        // xl
    float* bufB = bufA + NF;           // xr
    float* bufC = bufB + NF;           // h
    int* deg       = (int*)(bufC + NF);  // [N]
    int* row_ptr   = deg + N;            // [N+1]
    int* writeidx  = row_ptr + (N + 1);  // [N]
    int* csr_src   = writeidx + N;       // [E]
    int* blockSums = csr_src + E;        // [nBlk]
    int* blockOffs = blockSums + nBlk;   // [nBlk]

    float* outF = (float*)d_out;

    // --- CSR build (shared by both layers) ---
    zero_int_kernel<<<(N + 255) / 256, 256, 0, stream>>>(deg, N);
    count_deg_kernel<<<(E + 255) / 256, 256, 0, stream>>>(dst, deg, E);
    scan_blocksum_kernel<<<nBlk, 256, 0, stream>>>(deg, blockSums, N);
    scan_sums_kernel<<<1, 256, 0, stream>>>(blockSums, blockOffs, &row_ptr[N], nBlk);
    scan_apply_kernel<<<nBlk, 256, 0, stream>>>(deg, blockOffs, row_ptr, writeidx, N);
    scatter_edges_kernel<<<(E + 255) / 256, 256, 0, stream>>>(src, dst, writeidx, csr_src, E);

    dim3 gemmGrid((N + 127) / 128, 2);
    dim3 aggGrid((N + 3) / 4);

    // --- layer 1 ---
    gemm_dual_kernel<<<gemmGrid, 256, 0, stream>>>(x, Wl1, bl1, bufA, Wr1, br1, bufB, N);
    gat_aggregate_kernel<<<aggGrid, 256, 0, stream>>>(bufA, bufB, att1, b1, row_ptr, csr_src,
                                                      bufC, N, 1);
    // --- layer 2 ---
    gemm_dual_kernel<<<gemmGrid, 256, 0, stream>>>(bufC, Wl2, bl2, bufA, Wr2, br2, bufB, N);
    gat_aggregate_kernel<<<aggGrid, 256, 0, stream>>>(bufA, bufB, att2, b2, row_ptr, csr_src,
                                                      outF, N, 0);
}

// Round 3
// 407.511 us; speedup vs baseline: 1.3549x; 1.0116x over previous
//
#include <hip/hip_runtime.h>
#include <math.h>

// ---------------------------------------------------------------------------
// GATv2 2-layer GNN, fp32. N=50000, E=800000, F=128 (all dims).
//   1. build CSR by dst (memset -> count -> 3-kernel scan -> scatter)
//   2. GEMM x @ {Wl1,Wr1} + bias -> bufA (xl), bufB (xr)
//   3. aggregate: online-softmax, half-wave float4, 2 edges/wave in flight
//   4. GEMM bufC @ {Wl2,Wr2} + bias -> bufA, bufB
//   5. aggregate -> d_out (+ b2, no relu)
// ---------------------------------------------------------------------------

__global__ void count_deg_kernel(const int* __restrict__ dst, int* __restrict__ deg, int E) {
    int i = blockIdx.x * blockDim.x + threadIdx.x;
    if (i < E) atomicAdd(&deg[dst[i]], 1);
}

// --- hierarchical scan: pass 1 -- per-block (256 nodes) sums ---
__global__ __launch_bounds__(256) void scan_blocksum_kernel(const int* __restrict__ deg,
                                                            int* __restrict__ blockSums, int n) {
    __shared__ int wsum[4];
    int tid = threadIdx.x;
    int idx = blockIdx.x * 256 + tid;
    int v = (idx < n) ? deg[idx] : 0;
    int lane = tid & 63, wid = tid >> 6;
    #pragma unroll
    for (int off = 32; off > 0; off >>= 1) v += __shfl_xor(v, off);
    if (lane == 0) wsum[wid] = v;
    __syncthreads();
    if (tid == 0) blockSums[blockIdx.x] = wsum[0] + wsum[1] + wsum[2] + wsum[3];
}

// --- pass 2 -- single-block exclusive scan of block sums (chunked, any n) ---
__global__ __launch_bounds__(256) void scan_sums_kernel(int* __restrict__ blockSums,
                                                        int* __restrict__ blockOffs,
                                                        int* __restrict__ totalOut, int n) {
    __shared__ int wsumExcl[4];
    __shared__ int sTotal;
    int tid = threadIdx.x, lane = tid & 63, wid = tid >> 6;
    int carry = 0;
    for (int base = 0; base < n; base += 256) {
        int idx = base + tid;
        int v = (idx < n) ? blockSums[idx] : 0;
        int incl = v;
        #pragma unroll
        for (int off = 1; off < 64; off <<= 1) {
            int t = __shfl_up(incl, off);
            if (lane >= off) incl += t;
        }
        if (lane == 63) wsumExcl[wid] = incl;
        __syncthreads();
        if (tid == 0) {
            int a = wsumExcl[0], b = wsumExcl[1], c = wsumExcl[2], d = wsumExcl[3];
            wsumExcl[0] = 0; wsumExcl[1] = a; wsumExcl[2] = a + b; wsumExcl[3] = a + b + c;
            sTotal = a + b + c + d;
        }
        __syncthreads();
        if (idx < n) blockOffs[idx] = carry + wsumExcl[wid] + (incl - v);
        carry += sTotal;
        __syncthreads();
    }
    if (tid == 0) *totalOut = carry;
}

// --- pass 3 -- local scan + block offset -> row_ptr / writeidx ---
__global__ __launch_bounds__(256) void scan_apply_kernel(const int* __restrict__ deg,
                                                         const int* __restrict__ blockOffs,
                                                         int* __restrict__ row_ptr,
                                                         int* __restrict__ writeidx, int n) {
    __shared__ int wsum[4];
    int tid = threadIdx.x, lane = tid & 63, wid = tid >> 6;
    int idx = blockIdx.x * 256 + tid;
    int v = (idx < n) ? deg[idx] : 0;
    int incl = v;
    #pragma unroll
    for (int off = 1; off < 64; off <<= 1) {
        int t = __shfl_up(incl, off);
        if (lane >= off) incl += t;
    }
    if (lane == 63) wsum[wid] = incl;
    __syncthreads();
    int woff = 0;
    #pragma unroll
    for (int w = 0; w < 4; ++w) woff += (w < wid) ? wsum[w] : 0;
    int excl = blockOffs[blockIdx.x] + woff + (incl - v);
    if (idx < n) { row_ptr[idx] = excl; writeidx[idx] = excl; }
}

__global__ void scatter_edges_kernel(const int* __restrict__ src, const int* __restrict__ dst,
                                     int* __restrict__ writeidx, int* __restrict__ csr_src, int E) {
    int i = blockIdx.x * blockDim.x + threadIdx.x;
    if (i < E) {
        int d = dst[i];
        int pos = atomicAdd(&writeidx[d], 1);
        csr_src[pos] = src[i];
    }
}

// ---------------------------------------------------------------------------
// fp32 GEMM (unchanged): out = X @ W + b.
// ---------------------------------------------------------------------------
__global__ __launch_bounds__(256) void gemm_dual_kernel(
    const float* __restrict__ X,
    const float* __restrict__ W0, const float* __restrict__ b0, float* __restrict__ out0,
    const float* __restrict__ W1, const float* __restrict__ b1, float* __restrict__ out1,
    int Nrows) {
    const float* W = blockIdx.y ? W1 : W0;
    const float* bias = blockIdx.y ? b1 : b0;
    float* out = blockIdx.y ? out1 : out0;

    __shared__ float xs[32][128];
    __shared__ float wsh[32][128];

    int tid = threadIdx.x;
    int tx = tid & 15;
    int ty = tid >> 4;
    int m0 = blockIdx.x * 128;

    float acc[8][8] = {{0.f}};

    for (int k0 = 0; k0 < 128; k0 += 32) {
        #pragma unroll
        for (int r = 0; r < 4; ++r) {
            int row = (tid >> 3) + r * 32;
            int kseg = (tid & 7) * 4;
            int gr = m0 + row;
            if (gr >= Nrows) gr = Nrows - 1;
            const float4 v = *(const float4*)&X[(size_t)gr * 128 + k0 + kseg];
            xs[kseg + 0][row] = v.x;
            xs[kseg + 1][row] = v.y;
            xs[kseg + 2][row] = v.z;
            xs[kseg + 3][row] = v.w;
        }
        #pragma unroll
        for (int r = 0; r < 4; ++r) {
            int wrow = (tid >> 5) + r * 8;
            int wcol = (tid & 31) * 4;
            *(float4*)&wsh[wrow][wcol] = *(const float4*)&W[(size_t)(k0 + wrow) * 128 + wcol];
        }
        __syncthreads();
        #pragma unroll
        for (int k = 0; k < 32; ++k) {
            float a[8], b[8];
            *(float4*)&a[0] = *(float4*)&xs[k][ty * 8];
            *(float4*)&a[4] = *(float4*)&xs[k][ty * 8 + 4];
            *(float4*)&b[0] = *(float4*)&wsh[k][tx * 8];
            *(float4*)&b[4] = *(float4*)&wsh[k][tx * 8 + 4];
            #pragma unroll
            for (int i = 0; i < 8; ++i)
                #pragma unroll
                for (int j = 0; j < 8; ++j)
                    acc[i][j] += a[i] * b[j];
        }
        __syncthreads();
    }

    float bv[8];
    *(float4*)&bv[0] = *(const float4*)&bias[tx * 8];
    *(float4*)&bv[4] = *(const float4*)&bias[tx * 8 + 4];
    #pragma unroll
    for (int i = 0; i < 8; ++i) {
        int gr = m0 + ty * 8 + i;
        if (gr < Nrows) {
            float4 o0 = {acc[i][0] + bv[0], acc[i][1] + bv[1], acc[i][2] + bv[2], acc[i][3] + bv[3]};
            float4 o1 = {acc[i][4] + bv[4], acc[i][5] + bv[5], acc[i][6] + bv[6], acc[i][7] + bv[7]};
            *(float4*)&out[(size_t)gr * 128 + tx * 8] = o0;
            *(float4*)&out[(size_t)gr * 128 + tx * 8 + 4] = o1;
        }
    }
}

// ---------------------------------------------------------------------------
// Aggregation v3: one wave per node; half-wave float4 layout.
// Lanes 0-31 hold all 128 feats (float4) of even-pair edges, lanes 32-63 of
// odd-pair edges. Butterfly = 5 steps within half + 1 cross-half exchange.
// Online softmax state (m, dsum) duplicated identically in both halves;
// feature accumulators are per-half partials, combined at the end.
// ---------------------------------------------------------------------------
__global__ __launch_bounds__(256) void gat_aggregate_kernel(
    const float* __restrict__ xl, const float* __restrict__ xr,
    const float* __restrict__ att, const float* __restrict__ bias,
    const int* __restrict__ row_ptr, const int* __restrict__ csr_src,
    float* __restrict__ out, int N, int applyRelu) {
    int wid = threadIdx.x >> 6;
    int lane = threadIdx.x & 63;
    int hlane = lane & 31;   // position within half
    int half = lane >> 5;    // 0 or 1
    int node = blockIdx.x * 4 + wid;
    if (node >= N) return;

    const float4* xl4 = (const float4*)xl;
    float4 xrv = ((const float4*)xr)[(size_t)node * 32 + hlane];
    float4 attv = ((const float4*)att)[hlane];

    int beg = row_ptr[node];
    int end = row_ptr[node + 1];

    float m = -INFINITY;
    float dsum = 0.f;
    float4 acc = {0.f, 0.f, 0.f, 0.f};

    for (int cbase = beg; cbase < end; cbase += 64) {
        int cnt = end - cbase;
        if (cnt > 64) cnt = 64;
        int myidx = (lane < cnt) ? csr_src[cbase + lane] : 0;  // coalesced
        int npair = cnt >> 1;

        int j = 0;
        // --- batches of 4 pairs (8 edges in flight) ---
        for (; j + 4 <= npair; j += 4) {
            int b0 = 2 * j + half;
            int s0 = __shfl(myidx, b0 + 0);
            int s1 = __shfl(myidx, b0 + 2);
            int s2 = __shfl(myidx, b0 + 4);
            int s3 = __shfl(myidx, b0 + 6);
            float4 v0 = xl4[(size_t)s0 * 32 + hlane];
            float4 v1 = xl4[(size_t)s1 * 32 + hlane];
            float4 v2 = xl4[(size_t)s2 * 32 + hlane];
            float4 v3 = xl4[(size_t)s3 * 32 + hlane];

            float t, p0, p1, p2, p3;
            t = v0.x + xrv.x; t = t > 0.f ? t : 0.2f * t; p0 = t * attv.x;
            t = v0.y + xrv.y; t = t > 0.f ? t : 0.2f * t; p0 = fmaf(t, attv.y, p0);
            t = v0.z + xrv.z; t = t > 0.f ? t : 0.2f * t; p0 = fmaf(t, attv.z, p0);
            t = v0.w + xrv.w; t = t > 0.f ? t : 0.2f * t; p0 = fmaf(t, attv.w, p0);
            t = v1.x + xrv.x; t = t > 0.f ? t : 0.2f * t; p1 = t * attv.x;
            t = v1.y + xrv.y; t = t > 0.f ? t : 0.2f * t; p1 = fmaf(t, attv.y, p1);
            t = v1.z + xrv.z; t = t > 0.f ? t : 0.2f * t; p1 = fmaf(t, attv.z, p1);
            t = v1.w + xrv.w; t = t > 0.f ? t : 0.2f * t; p1 = fmaf(t, attv.w, p1);
            t = v2.x + xrv.x; t = t > 0.f ? t : 0.2f * t; p2 = t * attv.x;
            t = v2.y + xrv.y; t = t > 0.f ? t : 0.2f * t; p2 = fmaf(t, attv.y, p2);
            t = v2.z + xrv.z; t = t > 0.f ? t : 0.2f * t; p2 = fmaf(t, attv.z, p2);
            t = v2.w + xrv.w; t = t > 0.f ? t : 0.2f * t; p2 = fmaf(t, attv.w, p2);
            t = v3.x + xrv.x; t = t > 0.f ? t : 0.2f * t; p3 = t * attv.x;
            t = v3.y + xrv.y; t = t > 0.f ? t : 0.2f * t; p3 = fmaf(t, attv.y, p3);
            t = v3.z + xrv.z; t = t > 0.f ? t : 0.2f * t; p3 = fmaf(t, attv.z, p3);
            t = v3.w + xrv.w; t = t > 0.f ? t : 0.2f * t; p3 = fmaf(t, attv.w, p3);

            // 4 interleaved half-wave butterflies (offsets < 32 stay in half)
            #pragma unroll
            for (int off = 16; off > 0; off >>= 1) {
                p0 += __shfl_xor(p0, off);
                p1 += __shfl_xor(p1, off);
                p2 += __shfl_xor(p2, off);
                p3 += __shfl_xor(p3, off);
            }
            // other half's scores
            float q0 = __shfl_xor(p0, 32);
            float q1 = __shfl_xor(p1, 32);
            float q2 = __shfl_xor(p2, 32);
            float q3 = __shfl_xor(p3, 32);

            float mnew = fmaxf(fmaxf(fmaxf(p0, p1), fmaxf(p2, p3)),
                               fmaxf(fmaxf(q0, q1), fmaxf(q2, q3)));
            mnew = fmaxf(mnew, m);
            float scale = __expf(m - mnew);  // first batch: exp(-inf)=0
            float e0 = __expf(p0 - mnew);
            float e1 = __expf(p1 - mnew);
            float e2 = __expf(p2 - mnew);
            float e3 = __expf(p3 - mnew);
            float f0 = __expf(q0 - mnew);
            float f1 = __expf(q1 - mnew);
            float f2 = __expf(q2 - mnew);
            float f3 = __expf(q3 - mnew);
            dsum = dsum * scale + ((e0 + e1) + (e2 + e3)) + ((f0 + f1) + (f2 + f3));
            acc.x = fmaf(e3, v3.x, fmaf(e2, v2.x, fmaf(e1, v1.x, fmaf(e0, v0.x, acc.x * scale))));
            acc.y = fmaf(e3, v3.y, fmaf(e2, v2.y, fmaf(e1, v1.y, fmaf(e0, v0.y, acc.y * scale))));
            acc.z = fmaf(e3, v3.z, fmaf(e2, v2.z, fmaf(e1, v1.z, fmaf(e0, v0.z, acc.z * scale))));
            acc.w = fmaf(e3, v3.w, fmaf(e2, v2.w, fmaf(e1, v1.w, fmaf(e0, v0.w, acc.w * scale))));
            m = mnew;
        }
        // --- leftover pairs ---
        for (; j < npair; ++j) {
            int s = __shfl(myidx, 2 * j + half);
            float4 v = xl4[(size_t)s * 32 + hlane];
            float t, p;
            t = v.x + xrv.x; t = t > 0.f ? t : 0.2f * t; p = t * attv.x;
            t = v.y + xrv.y; t = t > 0.f ? t : 0.2f * t; p = fmaf(t, attv.y, p);
            t = v.z + xrv.z; t = t > 0.f ? t : 0.2f * t; p = fmaf(t, attv.z, p);
            t = v.w + xrv.w; t = t > 0.f ? t : 0.2f * t; p = fmaf(t, attv.w, p);
            #pragma unroll
            for (int off = 16; off > 0; off >>= 1) p += __shfl_xor(p, off);
            float q = __shfl_xor(p, 32);
            float mnew = fmaxf(m, fmaxf(p, q));
            float scale = __expf(m - mnew);
            float ep = __expf(p - mnew);
            float eq = __expf(q - mnew);
            dsum = dsum * scale + ep + eq;
            acc.x = fmaf(ep, v.x, acc.x * scale);
            acc.y = fmaf(ep, v.y, acc.y * scale);
            acc.z = fmaf(ep, v.z, acc.z * scale);
            acc.w = fmaf(ep, v.w, acc.w * scale);
            m = mnew;
        }
        // --- odd tail edge: both halves compute it; only half 0 accumulates ---
        if (cnt & 1) {
            int s = __shfl(myidx, cnt - 1);
            float4 v = xl4[(size_t)s * 32 + hlane];
            float t, p;
            t = v.x + xrv.x; t = t > 0.f ? t : 0.2f * t; p = t * attv.x;
            t = v.y + xrv.y; t = t > 0.f ? t : 0.2f * t; p = fmaf(t, attv.y, p);
            t = v.z + xrv.z; t = t > 0.f ? t : 0.2f * t; p = fmaf(t, attv.z, p);
            t = v.w + xrv.w; t = t > 0.f ? t : 0.2f * t; p = fmaf(t, attv.w, p);
            #pragma unroll
            for (int off = 16; off > 0; off >>= 1) p += __shfl_xor(p, off);
            float mnew = fmaxf(m, p);
            float scale = __expf(m - mnew);
            float e = __expf(p - mnew);
            dsum = dsum * scale + e;
            float w = (half == 0) ? e : 0.f;
            acc.x = fmaf(w, v.x, acc.x * scale);
            acc.y = fmaf(w, v.y, acc.y * scale);
            acc.z = fmaf(w, v.z, acc.z * scale);
            acc.w = fmaf(w, v.w, acc.w * scale);
            m = mnew;
        }
    }

    // combine the two halves' feature partials
    float4 oth;
    oth.x = __shfl_xor(acc.x, 32);
    oth.y = __shfl_xor(acc.y, 32);
    oth.z = __shfl_xor(acc.z, 32);
    oth.w = __shfl_xor(acc.w, 32);
    float inv = dsum > 0.f ? 1.f / dsum : 0.f;
    float4 bv = ((const float4*)bias)[hlane];
    float4 o;
    o.x = (acc.x + oth.x) * inv + bv.x;
    o.y = (acc.y + oth.y) * inv + bv.y;
    o.z = (acc.z + oth.z) * inv + bv.z;
    o.w = (acc.w + oth.w) * inv + bv.w;
    if (applyRelu) {
        o.x = fmaxf(o.x, 0.f); o.y = fmaxf(o.y, 0.f);
        o.z = fmaxf(o.z, 0.f); o.w = fmaxf(o.w, 0.f);
    }
    if (half == 0) ((float4*)out)[(size_t)node * 32 + hlane] = o;
}

// ---------------------------------------------------------------------------

extern "C" void kernel_launch(void* const* d_in, const int* in_sizes, int n_in,
                              void* d_out, int out_size, void* d_ws, size_t ws_size,
                              hipStream_t stream) {
    const float* x    = (const float*)d_in[0];
    const int* eidx   = (const int*)d_in[1];
    const float* Wl1  = (const float*)d_in[2];
    const float* bl1  = (const float*)d_in[3];
    const float* Wr1  = (const float*)d_in[4];
    const float* br1  = (const float*)d_in[5];
    const float* att1 = (const float*)d_in[6];
    const float* b1   = (const float*)d_in[7];
    const float* Wl2  = (const float*)d_in[8];
    const float* bl2  = (const float*)d_in[9];
    const float* Wr2  = (const float*)d_in[10];
    const float* br2  = (const float*)d_in[11];
    const float* att2 = (const float*)d_in[12];
    const float* b2   = (const float*)d_in[13];

    const int N = in_sizes[0] / 128;
    const int E = in_sizes[1] / 2;
    const int* src = eidx;
    const int* dst = eidx + E;

    const int nBlk = (N + 255) / 256;  // scan blocks

    // workspace layout
    size_t NF = (size_t)N * 128;
    float* bufA = (float*)d_ws;        // xl
    float* bufB = bufA + NF;           // xr
    float* bufC = bufB + NF;           // h
    int* deg       = (int*)(bufC + NF);  // [N]
    int* row_ptr   = deg + N;            // [N+1]
    int* writeidx  = row_ptr + (N + 1);  // [N]
    int* csr_src   = writeidx + N;       // [E]
    int* blockSums = csr_src + E;        // [nBlk]
    int* blockOffs = blockSums + nBlk;   // [nBlk]

    float* outF = (float*)d_out;

    // --- CSR build (shared by both layers) ---
    hipMemsetAsync(deg, 0, (size_t)N * sizeof(int), stream);
    count_deg_kernel<<<(E + 255) / 256, 256, 0, stream>>>(dst, deg, E);
    scan_blocksum_kernel<<<nBlk, 256, 0, stream>>>(deg, blockSums, N);
    scan_sums_kernel<<<1, 256, 0, stream>>>(blockSums, blockOffs, &row_ptr[N], nBlk);
    scan_apply_kernel<<<nBlk, 256, 0, stream>>>(deg, blockOffs, row_ptr, writeidx, N);
    scatter_edges_kernel<<<(E + 255) / 256, 256, 0, stream>>>(src, dst, writeidx, csr_src, E);

    dim3 gemmGrid((N + 127) / 128, 2);
    dim3 aggGrid((N + 3) / 4);

    // --- layer 1 ---
    gemm_dual_kernel<<<gemmGrid, 256, 0, stream>>>(x, Wl1, bl1, bufA, Wr1, br1, bufB, N);
    gat_aggregate_kernel<<<aggGrid, 256, 0, stream>>>(bufA, bufB, att1, b1, row_ptr, csr_src,
                                                      bufC, N, 1);
    // --- layer 2 ---
    gemm_dual_kernel<<<gemmGrid, 256, 0, stream>>>(bufC, Wl2, bl2, bufA, Wr2, br2, bufB, N);
    gat_aggregate_kernel<<<aggGrid, 256, 0, stream>>>(bufA, bufB, att2, b2, row_ptr, csr_src,
                                                      outF, N, 0);
}